// Round 3
// baseline (368.791 us; speedup 1.0000x reference)
//
#include <hip/hip_runtime.h>

// SpinorBilinears, direct-store formulation (no LDS, no barriers).
// Tokens = B*N = 524288, S=4, C=8. Outputs f32 concat: K0 | K1 | K2.
//
// One thread per output float4 of K1 (and the matching float4 of K2):
//   tau = token*16 + q,  q in [0,16):  c = q>>1, d0 = (q&1)*4
//   thread writes K1[token][c][d0..d0+3] and K2[token][c][d0..d0+3]
//
//   T[c][d]  = u[c] . v[d],  u[c] = psi^T Gc (row),  v[d] = Gd psi (col)
//   T[c][d]  = dot(u, a)  with a_i = dot(gd_i, p)        (Gd p)
//   T[d][c]  = dot(p, b)  with b_i = dot(gd_i, w), w = Gc p
//   K1 = 0.5(T - T^T), K2 = 0.5(T + T^T)
//
// gamma (512 B) stays L1-resident; psi loads are 16-lane same-address
// broadcasts; K1/K2 stores are perfectly coalesced (lane i -> 16B at i*16).

#define TPB 256

typedef float f32x4 __attribute__((ext_vector_type(4)));  // clang vector: valid for nontemporal builtins

__device__ __forceinline__ float dot4(float4 a, float4 b) {
    return a.x * b.x + a.y * b.y + a.z * b.z + a.w * b.w;
}

__global__ __launch_bounds__(TPB) void spinor_bilinears_direct(
    const float* __restrict__ psi,
    const float* __restrict__ gamma,
    float* __restrict__ out,
    long long n_tokens) {
    const long long tau = (long long)blockIdx.x * TPB + threadIdx.x;
    const long long token = tau >> 4;
    const int q = (int)(tau & 15);
    const int c = q >> 1;          // 0..7
    const int d0 = (q & 1) * 4;    // 0 or 4

    const float4* __restrict__ psi4 = (const float4*)psi;
    const float4* __restrict__ g4 = (const float4*)gamma;  // g4[cc*4+i] = gamma[cc][i][:]

    float* K0 = out;
    f32x4* K1 = (f32x4*)(out + n_tokens);
    f32x4* K2 = (f32x4*)(out + n_tokens + n_tokens * 64);

    // K0: first n_tokens threads handle it (coalesced float4 load + dword store)
    if (tau < n_tokens) {
        const float4 pp = psi4[tau];
        __builtin_nontemporal_store(dot4(pp, pp), &out[tau]);
    }

    const float4 p = psi4[token];  // 16 consecutive lanes share this address

    // Gc rows
    const float4 gc0 = g4[c * 4 + 0];
    const float4 gc1 = g4[c * 4 + 1];
    const float4 gc2 = g4[c * 4 + 2];
    const float4 gc3 = g4[c * 4 + 3];

    // u = psi^T Gc (column sums), w = Gc psi (row dots)
    float4 u, w;
    u.x = p.x * gc0.x + p.y * gc1.x + p.z * gc2.x + p.w * gc3.x;
    u.y = p.x * gc0.y + p.y * gc1.y + p.z * gc2.y + p.w * gc3.y;
    u.z = p.x * gc0.z + p.y * gc1.z + p.z * gc2.z + p.w * gc3.z;
    u.w = p.x * gc0.w + p.y * gc1.w + p.z * gc2.w + p.w * gc3.w;
    w.x = dot4(gc0, p);
    w.y = dot4(gc1, p);
    w.z = dot4(gc2, p);
    w.w = dot4(gc3, p);

    float k1a[4], k2a[4];
#pragma unroll
    for (int k = 0; k < 4; ++k) {
        const int d = d0 + k;
        const float4 gd0 = g4[d * 4 + 0];
        const float4 gd1 = g4[d * 4 + 1];
        const float4 gd2 = g4[d * 4 + 2];
        const float4 gd3 = g4[d * 4 + 3];

        // a = Gd p  (gives T[c][d] = u.a);  b = Gd w  (gives T[d][c] = p.b)
        const float a0 = dot4(gd0, p);
        const float a1 = dot4(gd1, p);
        const float a2 = dot4(gd2, p);
        const float a3 = dot4(gd3, p);
        const float b0 = dot4(gd0, w);
        const float b1 = dot4(gd1, w);
        const float b2 = dot4(gd2, w);
        const float b3 = dot4(gd3, w);

        const float tcd = u.x * a0 + u.y * a1 + u.z * a2 + u.w * a3;
        const float tdc = p.x * b0 + p.y * b1 + p.z * b2 + p.w * b3;

        k1a[k] = 0.5f * (tcd - tdc);
        k2a[k] = 0.5f * (tcd + tdc);
    }

    f32x4 o1, o2;
    o1.x = k1a[0]; o1.y = k1a[1]; o1.z = k1a[2]; o1.w = k1a[3];
    o2.x = k2a[0]; o2.y = k2a[1]; o2.z = k2a[2]; o2.w = k2a[3];
    __builtin_nontemporal_store(o1, &K1[tau]);
    __builtin_nontemporal_store(o2, &K2[tau]);
}

extern "C" void kernel_launch(void* const* d_in, const int* in_sizes, int n_in,
                              void* d_out, int out_size, void* d_ws, size_t ws_size,
                              hipStream_t stream) {
    const float* psi = (const float*)d_in[0];
    const float* gamma = (const float*)d_in[1];
    float* out = (float*)d_out;

    const long long n_tokens = (long long)in_sizes[0] / 4;   // B*N = 524288
    const long long n_threads = n_tokens * 16;               // one per K1 float4
    const int blocks = (int)(n_threads / TPB);               // 32768

    spinor_bilinears_direct<<<blocks, TPB, 0, stream>>>(psi, gamma, out, n_tokens);
}

// Round 4
// 273.359 us; speedup vs baseline: 1.3491x; 1.3491x over previous
//
#include <hip/hip_runtime.h>

// SpinorBilinears v3: thread-per-token (wave-uniform gamma -> SGPR s_loads),
// K1/K2 rows finished in registers, LDS used only as a store-coalescing
// transpose buffer. Single-wave blocks: no real barrier needed.
// Tokens = B*N = 524288, S=4, C=8. Outputs f32 concat: K0 | K1 | K2.

#define TPB 64        // one wave per block
#define STRIDE 68     // 64 + 4 pad: b128 LDS ops land 2-way/bank (= free)

typedef float f32x4 __attribute__((ext_vector_type(4)));

__device__ __forceinline__ float dot4(float4 a, float4 b) {
    return a.x * b.x + a.y * b.y + a.z * b.z + a.w * b.w;
}

__global__ __launch_bounds__(TPB) void spinor_bilinears_v3(
    const float* __restrict__ psi,
    const float* __restrict__ gamma,
    float* __restrict__ out,
    long long n_tokens) {
    __shared__ float lds1[TPB * STRIDE];   // K1 rows
    __shared__ float lds2[TPB * STRIDE];   // K2 rows

    const int lane = threadIdx.x;
    const long long t = (long long)blockIdx.x * TPB + lane;

    // ---- Phase 1: per-token compute (all gamma addresses wave-uniform) ----
    const float4 p = ((const float4*)psi)[t];
    out[t] = dot4(p, p);                   // K0, coalesced dword store

    const float4* g4 = (const float4*)gamma;  // g4[c*4+i] = gamma[c][i][:]
    float4 u[8], v[8];
#pragma unroll
    for (int c = 0; c < 8; ++c) {
        const float4 g0 = g4[c * 4 + 0];
        const float4 g1 = g4[c * 4 + 1];
        const float4 g2 = g4[c * 4 + 2];
        const float4 g3 = g4[c * 4 + 3];
        float4 uc;                          // u[c] = psi^T Gc
        uc.x = p.x * g0.x + p.y * g1.x + p.z * g2.x + p.w * g3.x;
        uc.y = p.x * g0.y + p.y * g1.y + p.z * g2.y + p.w * g3.y;
        uc.z = p.x * g0.z + p.y * g1.z + p.z * g2.z + p.w * g3.z;
        uc.w = p.x * g0.w + p.y * g1.w + p.z * g2.w + p.w * g3.w;
        u[c] = uc;
        float4 vc;                          // v[c] = Gc psi
        vc.x = dot4(g0, p);
        vc.y = dot4(g1, p);
        vc.z = dot4(g2, p);
        vc.w = dot4(g3, p);
        v[c] = vc;
    }

    // Full T[c][d] = u[c] . v[d] in registers (all indices static after unroll)
    float T[8][8];
#pragma unroll
    for (int c = 0; c < 8; ++c) {
#pragma unroll
        for (int d = 0; d < 8; ++d) {
            T[c][d] = dot4(u[c], v[d]);
        }
    }

    // Finished K1/K2 rows -> LDS via b128 writes (stride 68: 2-way, free)
    float* r1 = &lds1[lane * STRIDE];
    float* r2 = &lds2[lane * STRIDE];
#pragma unroll
    for (int c = 0; c < 8; ++c) {
#pragma unroll
        for (int h = 0; h < 2; ++h) {
            const int d0 = h * 4;
            f32x4 k1q, k2q;
#pragma unroll
            for (int k = 0; k < 4; ++k) {
                const float tcd = T[c][d0 + k];
                const float tdc = T[d0 + k][c];
                k1q[k] = 0.5f * (tcd - tdc);
                k2q[k] = 0.5f * (tcd + tdc);
            }
            *(f32x4*)(r1 + c * 8 + d0) = k1q;
            *(f32x4*)(r2 + c * 8 + d0) = k2q;
        }
    }

    __syncthreads();  // single-wave block: effectively just a waitcnt

    // ---- Phase 2: pure streaming. Block region = 64 tokens * 16 quads ----
    const long long blk = (long long)blockIdx.x * (TPB * 16);
    f32x4* K1v = (f32x4*)(out + n_tokens) + blk;
    f32x4* K2v = (f32x4*)(out + n_tokens + n_tokens * 64) + blk;

#pragma unroll
    for (int i = 0; i < 16; ++i) {
        const int g = i * 64 + lane;        // consecutive lanes -> consecutive 16B
        const int tl = g >> 4;              // local token
        const int qq = g & 15;              // quad within the 64-float row
        const f32x4 q1 = *(const f32x4*)(&lds1[tl * STRIDE + qq * 4]);
        const f32x4 q2 = *(const f32x4*)(&lds2[tl * STRIDE + qq * 4]);
        K1v[g] = q1;
        K2v[g] = q2;
    }
}

extern "C" void kernel_launch(void* const* d_in, const int* in_sizes, int n_in,
                              void* d_out, int out_size, void* d_ws, size_t ws_size,
                              hipStream_t stream) {
    const float* psi = (const float*)d_in[0];
    const float* gamma = (const float*)d_in[1];
    float* out = (float*)d_out;

    const long long n_tokens = (long long)in_sizes[0] / 4;  // B*N = 524288
    const int blocks = (int)(n_tokens / TPB);               // 8192

    spinor_bilinears_v3<<<blocks, TPB, 0, stream>>>(psi, gamma, out, n_tokens);
}

// Round 5
// 272.208 us; speedup vs baseline: 1.3548x; 1.0042x over previous
//
#include <hip/hip_runtime.h>

// SpinorBilinears v4: occupancy-focused.
// 256-thread blocks, 64 tokens/block, LDS holds raw T only (17.4 KB).
// Phase 1: waves 0..1 compute T halves (wave-uniform gamma -> s_loads).
// Phase 2: all 4 waves stream K1/K2 with nontemporal coalesced stores.
// Tokens = B*N = 524288, S=4, C=8. Outputs f32 concat: K0 | K1 | K2.

#define TPB 256
#define TOK 64        // tokens per block
#define STRIDE 68     // 64 + 4 pad: bank-balanced b128 LDS ops (verified r0)

typedef float f32x4 __attribute__((ext_vector_type(4)));

__device__ __forceinline__ float dot4(float4 a, float4 b) {
    return a.x * b.x + a.y * b.y + a.z * b.z + a.w * b.w;
}

__global__ __launch_bounds__(TPB) void spinor_bilinears_v4(
    const float* __restrict__ psi,
    const float* __restrict__ gamma,
    float* __restrict__ out,
    long long n_tokens) {
    __shared__ float ldsT[TOK * STRIDE];   // 17408 B

    const int tid = threadIdx.x;
    const int wave = tid >> 6;
    const int lane = tid & 63;

    // ---- Phase 1: waves 0,1 compute token T-halves ----
    if (wave < 2) {
        const long long t = (long long)blockIdx.x * TOK + lane;
        const float4 p = ((const float4*)psi)[t];
        if (wave == 0) {
            __builtin_nontemporal_store(dot4(p, p), &out[t]);  // K0
        }
        const float4* g4 = (const float4*)gamma;  // g4[c*4+i] = gamma[c][i][:]

        // v[d] = Gd psi, all d (wave-uniform gamma addresses)
        float4 v[8];
#pragma unroll
        for (int d = 0; d < 8; ++d) {
            const float4 g0 = g4[d * 4 + 0];
            const float4 g1 = g4[d * 4 + 1];
            const float4 g2 = g4[d * 4 + 2];
            const float4 g3 = g4[d * 4 + 3];
            float4 vd;
            vd.x = dot4(g0, p);
            vd.y = dot4(g1, p);
            vd.z = dot4(g2, p);
            vd.w = dot4(g3, p);
            v[d] = vd;
        }

        // u[c] = psi^T Gc for this wave's half; T rows -> LDS immediately
        float* trow = &ldsT[lane * STRIDE];
#pragma unroll
        for (int i = 0; i < 4; ++i) {
            const int c = wave * 4 + i;    // wave-uniform
            const float4 g0 = g4[c * 4 + 0];
            const float4 g1 = g4[c * 4 + 1];
            const float4 g2 = g4[c * 4 + 2];
            const float4 g3 = g4[c * 4 + 3];
            float4 u;
            u.x = p.x * g0.x + p.y * g1.x + p.z * g2.x + p.w * g3.x;
            u.y = p.x * g0.y + p.y * g1.y + p.z * g2.y + p.w * g3.y;
            u.z = p.x * g0.z + p.y * g1.z + p.z * g2.z + p.w * g3.z;
            u.w = p.x * g0.w + p.y * g1.w + p.z * g2.w + p.w * g3.w;
            f32x4 q0, q1;
            q0[0] = dot4(u, v[0]); q0[1] = dot4(u, v[1]);
            q0[2] = dot4(u, v[2]); q0[3] = dot4(u, v[3]);
            q1[0] = dot4(u, v[4]); q1[1] = dot4(u, v[5]);
            q1[2] = dot4(u, v[6]); q1[3] = dot4(u, v[7]);
            *(f32x4*)(trow + c * 8 + 0) = q0;
            *(f32x4*)(trow + c * 8 + 4) = q1;
        }
    }

    __syncthreads();

    // ---- Phase 2: stream K1/K2, 1024 quads per block, 4 iters/thread ----
    const long long blk = (long long)blockIdx.x * (TOK * 16);
    f32x4* K1v = (f32x4*)(out + n_tokens) + blk;
    f32x4* K2v = (f32x4*)(out + n_tokens + n_tokens * 64) + blk;

#pragma unroll
    for (int it = 0; it < 4; ++it) {
        const int item = it * TPB + tid;
        const int tl = item >> 4;          // local token
        const int cd0 = (item & 15) * 4;   // flat offset in 64-float row
        const int c = cd0 >> 3;
        const int d0 = cd0 & 7;            // 0 or 4
        const float* trow = &ldsT[tl * STRIDE];

        const f32x4 tcd = *(const f32x4*)(trow + cd0);   // T[c][d0..d0+3]
        const float td0 = trow[(d0 + 0) * 8 + c];        // T[d][c]
        const float td1 = trow[(d0 + 1) * 8 + c];
        const float td2 = trow[(d0 + 2) * 8 + c];
        const float td3 = trow[(d0 + 3) * 8 + c];

        f32x4 o1, o2;
        o1[0] = 0.5f * (tcd[0] - td0);  o2[0] = 0.5f * (tcd[0] + td0);
        o1[1] = 0.5f * (tcd[1] - td1);  o2[1] = 0.5f * (tcd[1] + td1);
        o1[2] = 0.5f * (tcd[2] - td2);  o2[2] = 0.5f * (tcd[2] + td2);
        o1[3] = 0.5f * (tcd[3] - td3);  o2[3] = 0.5f * (tcd[3] + td3);

        __builtin_nontemporal_store(o1, &K1v[item]);   // lane-consecutive 16B
        __builtin_nontemporal_store(o2, &K2v[item]);
    }
}

extern "C" void kernel_launch(void* const* d_in, const int* in_sizes, int n_in,
                              void* d_out, int out_size, void* d_ws, size_t ws_size,
                              hipStream_t stream) {
    const float* psi = (const float*)d_in[0];
    const float* gamma = (const float*)d_in[1];
    float* out = (float*)d_out;

    const long long n_tokens = (long long)in_sizes[0] / 4;  // B*N = 524288
    const int blocks = (int)(n_tokens / TOK);               // 8192

    spinor_bilinears_v4<<<blocks, TPB, 0, stream>>>(psi, gamma, out, n_tokens);
}